// Round 2
// baseline (261.846 us; speedup 1.0000x reference)
//
#include <hip/hip_runtime.h>

// VectorQuantizer forward: N=131072 rows of D=64 vs K=1024 codes.
// Outputs flat fp32: [quantized_st (N*D), loss (1), indices-as-float (N)].
//
// Two-tier exactness scheme (validated earlier, absmax 0):
//  - vq_main: bf16 hi/lo split MFMA approx of g[k] = e2[k] - 2*dot (x2 dropped:
//    argmin and the best/second gap are invariant to the per-row constant).
//    Rows with (sec - best) < MARGIN are flagged for exact treatment.
//  - vq_cleanup: flagged rows re-scanned with bit-exact numerics
//    (sequential fmaf dot, (x2+e2)-2*dot, key-packed (dist,idx) min).
// B-matrix is pre-swizzled into MFMA fragment order so the K-loop has NO LDS
// and NO barriers: each lane reads its B-frags as contiguous global b128 loads.
//
// Round 2:
//  * REVERTED the manual register double-buffer (round-1 regression: compiler
//    already software-pipelines the single-buffer loop; manual version raised
//    VGPR 60->84 and added ~28us of stall).
//  * KEPT (-2*w) prepack + e2-folded-into-MFMA-C-init (validated round 1).
//  * NEW packed-key argmin epilogue: code idx lives in the low 10 mantissa
//    bits of the fp32 distance (monotone truncation; ties/perturbation caught
//    by the flag margin, raised 5e-5 -> 1e-4 to absorb <=2*1023 ulp masking).
//    Per element: and_or + fmed3 + fmin (3 VALU) vs cmp/min/max/2*cndmask/fmaf.

#define NROWS 131072
#define DIM 64
#define KCODES 1024
#define MARGIN 1e-4f
#define LOSS_SCALE (1.25f / ((float)NROWS * (float)DIM))

typedef short bf16x8 __attribute__((ext_vector_type(8)));
typedef float f32x4 __attribute__((ext_vector_type(4)));

__device__ __forceinline__ short f2bf(float f) {
    unsigned u = __float_as_uint(f);
    u += 0x7FFF + ((u >> 16) & 1);   // RNE
    return (short)(u >> 16);
}
__device__ __forceinline__ float bf2f(short h) {
    return __uint_as_float(((unsigned)(unsigned short)h) << 16);
}

// Per code k: e2[k] by sequential fmaf (bit-pattern the cleanup relies on),
// plus bf16 hi/lo split of (-2*w) stored in MFMA B-frag order:
//   short index = ((((t*2+ct)*2+kc)*4+q)*16 + m)*8 + j
//   where k = t*32 + ct*16 + m, d = kc*32 + q*8 + j.
// Thread k==0 also zeroes loss + flag counter (replaces two hipMemsetAsync).
__global__ __launch_bounds__(256) void prep_w(const float* __restrict__ w,
                                              float* __restrict__ e2,
                                              short* __restrict__ w_hi,
                                              short* __restrict__ w_lo,
                                              float* __restrict__ out_loss,
                                              unsigned* __restrict__ flag_cnt) {
    int k = blockIdx.x * blockDim.x + threadIdx.x;
    if (k == 0) { *out_loss = 0.0f; *flag_cnt = 0u; }
    if (k >= KCODES) return;
    const float* wk = w + (size_t)k * DIM;
    float r[DIM];
#pragma unroll
    for (int i = 0; i < DIM / 4; ++i) *(float4*)&r[4 * i] = *(const float4*)(wk + 4 * i);
    float s = 0.f;
#pragma unroll
    for (int d = 0; d < DIM; ++d) s = fmaf(r[d], r[d], s);
    e2[k] = s;

    const int t = k >> 5, ct = (k >> 4) & 1, m = k & 15;
#pragma unroll
    for (int kc = 0; kc < 2; ++kc)
#pragma unroll
        for (int q = 0; q < 4; ++q) {
            bf16x8 hv, lv;
#pragma unroll
            for (int j = 0; j < 8; ++j) {
                float f = -2.0f * r[kc * 32 + q * 8 + j];   // exact scale
                short h = f2bf(f);
                hv[j] = h;
                lv[j] = f2bf(f - bf2f(h));
            }
            size_t fo = ((size_t)(((t * 2 + ct) * 2 + kc) * 4 + q) * 16 + m) * 8;
            *(bf16x8*)(w_hi + fo) = hv;
            *(bf16x8*)(w_lo + fo) = lv;
        }
}

// Block: 4 independent waves x 32 rows = 128 rows. No barriers in the K-loop.
__global__ __launch_bounds__(256, 4) void vq_main(
        const float* __restrict__ x, const float* __restrict__ w,
        const float* __restrict__ e2,
        const short* __restrict__ w_hi, const short* __restrict__ w_lo,
        float* __restrict__ out_q, float* __restrict__ out_loss,
        float* __restrict__ out_idx,
        unsigned* __restrict__ flag_cnt, unsigned* __restrict__ flag_list) {
    const int tid = threadIdx.x;
    const int lane = tid & 63;
    const int wv = tid >> 6;
    const int m = lane & 15;
    const int q = lane >> 4;
    const int block_row0 = blockIdx.x * 128;
    const int wave_row0 = block_row0 + wv * 32;

    __shared__ int sidx[128];
    __shared__ unsigned char sflg[128];
    __shared__ float red[4];

    // ---- A operand: 2 rowtiles x 2 k-chunks; A[m][k=q*8+j] ----
    float xa[2][2][8];
#pragma unroll
    for (int rt = 0; rt < 2; ++rt) {
        const float* xr = x + (size_t)(wave_row0 + rt * 16 + m) * DIM + q * 8;
        *(float4*)&xa[rt][0][0] = *(const float4*)(xr);
        *(float4*)&xa[rt][0][4] = *(const float4*)(xr + 4);
        *(float4*)&xa[rt][1][0] = *(const float4*)(xr + 32);
        *(float4*)&xa[rt][1][4] = *(const float4*)(xr + 36);
    }
    bf16x8 ah[2][2], al[2][2];
#pragma unroll
    for (int rt = 0; rt < 2; ++rt)
#pragma unroll
        for (int c = 0; c < 2; ++c)
#pragma unroll
            for (int j = 0; j < 8; ++j) {
                float f = xa[rt][c][j];
                short h = f2bf(f);
                ah[rt][c][j] = h;
                al[rt][c][j] = f2bf(f - bf2f(h));
            }

    // Packed keys: high 22 bits = fp32 distance bits (truncated), low 10 = code.
    float best[2][4], sec[2][4];
#pragma unroll
    for (int rt = 0; rt < 2; ++rt)
#pragma unroll
        for (int r = 0; r < 4; ++r) {
            best[rt][r] = 3.4e38f;
            sec[rt][r] = 3.4e38f;
        }

    // Per-lane B pointers into frag-ordered arrays; tile stride 2048 shorts.
    const short* ph = w_hi + q * 128 + m * 8;
    const short* pl = w_lo + q * 128 + m * 8;
    const float* pe = e2 + m;

    for (int t = 0; t < KCODES / 32; ++t) {
        bf16x8 bh[2][2], bl[2][2];
#pragma unroll
        for (int ct = 0; ct < 2; ++ct)
#pragma unroll
            for (int kc = 0; kc < 2; ++kc) {
                int off = t * 2048 + (ct * 2 + kc) * 512;
                bh[ct][kc] = *(const bf16x8*)(ph + off);
                bl[ct][kc] = *(const bf16x8*)(pl + off);
            }
        float e2c0 = pe[t * 32];
        float e2c1 = pe[t * 32 + 16];

#pragma unroll
        for (int rt = 0; rt < 2; ++rt)
#pragma unroll
            for (int ct = 0; ct < 2; ++ct) {
                float ei = ct ? e2c1 : e2c0;
                f32x4 a = {ei, ei, ei, ei};
                a = __builtin_amdgcn_mfma_f32_16x16x32_bf16(al[rt][0], bh[ct][0], a, 0, 0, 0);
                a = __builtin_amdgcn_mfma_f32_16x16x32_bf16(ah[rt][0], bl[ct][0], a, 0, 0, 0);
                a = __builtin_amdgcn_mfma_f32_16x16x32_bf16(ah[rt][0], bh[ct][0], a, 0, 0, 0);
                a = __builtin_amdgcn_mfma_f32_16x16x32_bf16(al[rt][1], bh[ct][1], a, 0, 0, 0);
                a = __builtin_amdgcn_mfma_f32_16x16x32_bf16(ah[rt][1], bl[ct][1], a, 0, 0, 0);
                a = __builtin_amdgcn_mfma_f32_16x16x32_bf16(ah[rt][1], bh[ct][1], a, 0, 0, 0);
                unsigned id = (unsigned)(t * 32 + ct * 16 + m);
#pragma unroll
                for (int r = 0; r < 4; ++r) {
                    unsigned kb = (__float_as_uint(a[r]) & 0xFFFFFC00u) | id;
                    float kf = __uint_as_float(kb);
                    // median trick: new sec = median(key, old best, old sec)
                    sec[rt][r] = __builtin_amdgcn_fmed3f(kf, best[rt][r], sec[rt][r]);
                    best[rt][r] = fminf(best[rt][r], kf);
                }
            }
    }

    // cross-lane reduce over the 16 m-lanes; key order already encodes
    // value-then-lower-idx (ties caught by the flag margin anyway)
#pragma unroll
    for (int off = 1; off < 16; off <<= 1)
#pragma unroll
        for (int rt = 0; rt < 2; ++rt)
#pragma unroll
            for (int r = 0; r < 4; ++r) {
                float ob = __shfl_xor(best[rt][r], off, 64);
                float os = __shfl_xor(sec[rt][r], off, 64);
                sec[rt][r] = fminf(fminf(sec[rt][r], os), fmaxf(best[rt][r], ob));
                best[rt][r] = fminf(best[rt][r], ob);
            }

    if (m == 0) {
#pragma unroll
        for (int rt = 0; rt < 2; ++rt)
#pragma unroll
            for (int r = 0; r < 4; ++r) {
                unsigned bb = __float_as_uint(best[rt][r]);
                int code = (int)(bb & 1023u);
                float bestm = __uint_as_float(bb & 0xFFFFFC00u);
                float secm = __uint_as_float(__float_as_uint(sec[rt][r]) & 0xFFFFFC00u);
                int lr = wv * 32 + rt * 16 + q * 4 + r;
                sidx[lr] = code;
                bool fl = (secm - bestm) < MARGIN;
                sflg[lr] = fl ? 1 : 0;
                if (fl) {
                    unsigned p = atomicAdd(flag_cnt, 1u);
                    flag_list[p] = (unsigned)(block_row0 + lr);
                }
            }
    }
    __syncthreads();

    // ---- output pass: 2 x 64 rows, 4 threads/row ----
    float lsum = 0.f;
    const int rl = tid >> 2, part = tid & 3;
#pragma unroll
    for (int p = 0; p < 2; ++p) {
        int lr = p * 64 + rl;
        int grow = block_row0 + lr;
        if (!sflg[lr]) {
            int bi = sidx[lr];
            const float* xs = x + (size_t)grow * DIM + part * 16;
            const float* ws = w + (size_t)bi * DIM + part * 16;
            float* os = out_q + (size_t)grow * DIM + part * 16;
#pragma unroll
            for (int i = 0; i < 4; ++i) {
                float4 xv = *(const float4*)(xs + 4 * i);
                float4 wv4 = *(const float4*)(ws + 4 * i);
                float d0 = wv4.x - xv.x, d1 = wv4.y - xv.y;
                float d2 = wv4.z - xv.z, d3 = wv4.w - xv.w;
                lsum = fmaf(d0, d0, lsum);
                lsum = fmaf(d1, d1, lsum);
                lsum = fmaf(d2, d2, lsum);
                lsum = fmaf(d3, d3, lsum);
                float4 o = {xv.x + d0, xv.y + d1, xv.z + d2, xv.w + d3};
                *(float4*)(os + 4 * i) = o;
            }
            if (part == 0) out_idx[grow] = (float)bi;
        }
    }

    for (int off = 32; off > 0; off >>= 1) lsum += __shfl_down(lsum, off, 64);
    if ((tid & 63) == 0) red[tid >> 6] = lsum;
    __syncthreads();
    if (tid == 0) {
        float s = (red[0] + red[1]) + (red[2] + red[3]);
        atomicAdd(out_loss, s * LOSS_SCALE);
    }
}

// Exact re-scan of flagged rows (round-1 numerics). b128 LDS reads; the fmaf
// chain stays in ascending-d order -> bit-identical dots.
#define CH 16
__global__ __launch_bounds__(256) void vq_cleanup(
        const float* __restrict__ x, const float* __restrict__ w,
        const float* __restrict__ e2,
        const unsigned* __restrict__ flag_cnt,
        const unsigned* __restrict__ flag_list,
        float* __restrict__ out_q, float* __restrict__ out_loss,
        float* __restrict__ out_idx) {
    __shared__ float xs[CH][68];
    __shared__ float wt[128][68];
    __shared__ float sx2[CH];
    const int tid = threadIdx.x;
    const int rowsub = tid >> 4;    // 0..15
    const int kslot = tid & 15;
    const unsigned cnt = *flag_cnt;

    for (unsigned base = blockIdx.x * CH; base < cnt; base += gridDim.x * CH) {
        const int nrows = (int)min((unsigned)CH, cnt - base);
        __syncthreads();
        {
            int rr = tid >> 4, sg = tid & 15;
            if (rr < nrows) {
                unsigned grow = flag_list[base + rr];
                *(float4*)&xs[rr][sg * 4] =
                    *(const float4*)(x + (size_t)grow * DIM + sg * 4);
            }
        }
        __syncthreads();
        if (tid < nrows) {
            float s = 0.f;
#pragma unroll
            for (int d = 0; d < DIM; ++d) s = fmaf(xs[tid][d], xs[tid][d], s);
            sx2[tid] = s;
        }

        unsigned long long kmin = ~0ULL;
        for (int tile = 0; tile < KCODES / 128; ++tile) {
            __syncthreads();
#pragma unroll
            for (int i = 0; i < 8; ++i) {
                int f = tid + i * 256;
                int code = f >> 4, sg = f & 15;
                *(float4*)&wt[code][sg * 4] =
                    *(const float4*)(w + (size_t)(tile * 128 + code) * DIM + sg * 4);
            }
            __syncthreads();
            if (rowsub < nrows) {
#pragma unroll
                for (int j = 0; j < 8; ++j) {
                    int cl = j * 16 + kslot;
                    int code = tile * 128 + cl;
                    float dot = 0.f;
#pragma unroll
                    for (int d4 = 0; d4 < 16; ++d4) {
                        float4 wv4 = *(const float4*)&wt[cl][d4 * 4];
                        float4 xv4 = *(const float4*)&xs[rowsub][d4 * 4];
                        dot = fmaf(wv4.x, xv4.x, dot);
                        dot = fmaf(wv4.y, xv4.y, dot);
                        dot = fmaf(wv4.z, xv4.z, dot);
                        dot = fmaf(wv4.w, xv4.w, dot);
                    }
                    float dist = (sx2[rowsub] + e2[code]) - 2.0f * dot;
                    unsigned long long key =
                        ((unsigned long long)__float_as_uint(dist) << 32) |
                        (unsigned)code;
                    kmin = kmin < key ? kmin : key;
                }
            }
        }
#pragma unroll
        for (int off = 1; off < 16; off <<= 1) {
            unsigned long long o = __shfl_xor(kmin, off, 64);
            kmin = kmin < o ? kmin : o;
        }
        if (rowsub < nrows) {
            int bi = (int)(unsigned)(kmin & 0xFFFFFFFFu);
            unsigned grow = flag_list[base + rowsub];
            float4 x4 = *(float4*)&xs[rowsub][kslot * 4];
            float4 w4 = *(const float4*)(w + (size_t)bi * DIM + kslot * 4);
            float d0 = w4.x - x4.x, d1 = w4.y - x4.y;
            float d2 = w4.z - x4.z, d3 = w4.w - x4.w;
            float ls = 0.f;
            ls = fmaf(d0, d0, ls);
            ls = fmaf(d1, d1, ls);
            ls = fmaf(d2, d2, ls);
            ls = fmaf(d3, d3, ls);
            float4 o = {x4.x + d0, x4.y + d1, x4.z + d2, x4.w + d3};
            *(float4*)(out_q + (size_t)grow * DIM + kslot * 4) = o;
            if (kslot == 0) out_idx[grow] = (float)bi;
#pragma unroll
            for (int off = 1; off < 16; off <<= 1)
                ls += __shfl_xor(ls, off, 64);
            if (kslot == 0) atomicAdd(out_loss, ls * LOSS_SCALE);
        }
    }
}

extern "C" void kernel_launch(void* const* d_in, const int* in_sizes, int n_in,
                              void* d_out, int out_size, void* d_ws, size_t ws_size,
                              hipStream_t stream) {
    const float* x = (const float*)d_in[0];   // [N, D]
    const float* w = (const float*)d_in[1];   // [K, D]

    float* out_q    = (float*)d_out;
    float* out_loss = (float*)d_out + (size_t)NROWS * DIM;
    float* out_idx  = out_loss + 1;

    // ws: e2 (4KB) | w_hi frag-order (128KB) | w_lo (128KB) | cnt | list (512KB)
    float* e2 = (float*)d_ws;
    short* w_hi = (short*)(e2 + KCODES);
    short* w_lo = w_hi + (size_t)KCODES * DIM;
    unsigned* cnt = (unsigned*)(w_lo + (size_t)KCODES * DIM);
    unsigned* list = cnt + 1;

    prep_w<<<(KCODES + 255) / 256, 256, 0, stream>>>(w, e2, w_hi, w_lo,
                                                     out_loss, cnt);
    vq_main<<<NROWS / 128, 256, 0, stream>>>(x, w, e2, w_hi, w_lo,
                                             out_q, out_loss, out_idx, cnt, list);
    vq_cleanup<<<256, 256, 0, stream>>>(x, w, e2, cnt, list,
                                        out_q, out_loss, out_idx);
}

// Round 4
// 211.592 us; speedup vs baseline: 1.2375x; 1.2375x over previous
//
#include <hip/hip_runtime.h>

// VectorQuantizer forward: N=131072 rows of D=64 vs K=1024 codes.
// Outputs flat fp32: [quantized_st (N*D), loss (1), indices-as-float (N)].
//
// Two-tier exactness scheme (validated, absmax 0):
//  - vq_main: bf16 hi/lo split MFMA approx of g[k] = e2[k] - 2*dot (x2 dropped:
//    argmin and the best/second gap are invariant to the per-row constant).
//    Rows with (sec - best) < MARGIN are flagged for exact treatment.
//  - vq_cleanup: flagged rows re-scanned with bit-exact numerics
//    (sequential fmaf dot, (x2+e2)-2*dot, key-packed (dist,idx) min).
//
// Round 4 == round 3 resubmit (container failed twice; kernel audited clean:
// in-bounds gload_lds, wave-uniform LDS bases, uniform barriers, literal size).
//  * REVERTED packed-key epilogue (R2: dur insensitive to VALU count, and the
//    widened MARGIN 1e-4 cost ~45us of cleanup). Back to R0 epilogue + 5e-5.
//  * KEPT (-2*w) prepack + e2-folded-into-MFMA-C-init + memset merge.
//  * NEW: LDS staging of B tiles. Diagnosis: 16 waves/CU each re-read the full
//    256KB B stream from L2 (4MB/CU, ~39us of L2 BW) with no prefetch room at
//    VGPR=60 -> load-latency serialized, MFMA pipe fed 25%. Now each block
//    stages the 8KB tile once via global_load_lds (width 16, linear lane
//    order == frag order), double-buffered, one barrier/tile; stage of t+1
//    issues before compute of t so latency hides under MFMAs.

#define NROWS 131072
#define DIM 64
#define KCODES 1024
#define MARGIN 5e-5f
#define LOSS_SCALE (1.25f / ((float)NROWS * (float)DIM))

typedef short bf16x8 __attribute__((ext_vector_type(8)));
typedef float f32x4 __attribute__((ext_vector_type(4)));

__device__ __forceinline__ short f2bf(float f) {
    unsigned u = __float_as_uint(f);
    u += 0x7FFF + ((u >> 16) & 1);   // RNE
    return (short)(u >> 16);
}
__device__ __forceinline__ float bf2f(short h) {
    return __uint_as_float(((unsigned)(unsigned short)h) << 16);
}

__device__ __forceinline__ void gload_lds16(const short* g, short* l) {
    __builtin_amdgcn_global_load_lds(
        (const __attribute__((address_space(1))) void*)g,
        (__attribute__((address_space(3))) void*)l, 16, 0, 0);
}

// Per code k: e2[k] by sequential fmaf (bit-pattern the cleanup relies on),
// plus bf16 hi/lo split of (-2*w) stored in MFMA B-frag order:
//   short index = ((((t*2+ct)*2+kc)*4+q)*16 + m)*8 + j
//   where k = t*32 + ct*16 + m, d = kc*32 + q*8 + j.
// Thread k==0 also zeroes loss + flag counter (replaces two hipMemsetAsync).
__global__ __launch_bounds__(256) void prep_w(const float* __restrict__ w,
                                              float* __restrict__ e2,
                                              short* __restrict__ w_hi,
                                              short* __restrict__ w_lo,
                                              float* __restrict__ out_loss,
                                              unsigned* __restrict__ flag_cnt) {
    int k = blockIdx.x * blockDim.x + threadIdx.x;
    if (k == 0) { *out_loss = 0.0f; *flag_cnt = 0u; }
    if (k >= KCODES) return;
    const float* wk = w + (size_t)k * DIM;
    float r[DIM];
#pragma unroll
    for (int i = 0; i < DIM / 4; ++i) *(float4*)&r[4 * i] = *(const float4*)(wk + 4 * i);
    float s = 0.f;
#pragma unroll
    for (int d = 0; d < DIM; ++d) s = fmaf(r[d], r[d], s);
    e2[k] = s;

    const int t = k >> 5, ct = (k >> 4) & 1, m = k & 15;
#pragma unroll
    for (int kc = 0; kc < 2; ++kc)
#pragma unroll
        for (int q = 0; q < 4; ++q) {
            bf16x8 hv, lv;
#pragma unroll
            for (int j = 0; j < 8; ++j) {
                float f = -2.0f * r[kc * 32 + q * 8 + j];   // exact scale
                short h = f2bf(f);
                hv[j] = h;
                lv[j] = f2bf(f - bf2f(h));
            }
            size_t fo = ((size_t)(((t * 2 + ct) * 2 + kc) * 4 + q) * 16 + m) * 8;
            *(bf16x8*)(w_hi + fo) = hv;
            *(bf16x8*)(w_lo + fo) = lv;
        }
}

// Block: 4 waves x 32 rows = 128 rows. B tiles staged in LDS, double-buffered;
// one __syncthreads per tile (drains vmcnt for the stage + lgkm for ds_reads).
__global__ __launch_bounds__(256, 4) void vq_main(
        const float* __restrict__ x, const float* __restrict__ w,
        const float* __restrict__ e2,
        const short* __restrict__ w_hi, const short* __restrict__ w_lo,
        float* __restrict__ out_q, float* __restrict__ out_loss,
        float* __restrict__ out_idx,
        unsigned* __restrict__ flag_cnt, unsigned* __restrict__ flag_list) {
    const int tid = threadIdx.x;
    const int lane = tid & 63;
    const int wv = tid >> 6;
    const int m = lane & 15;
    const int q = lane >> 4;
    const int block_row0 = blockIdx.x * 128;
    const int wave_row0 = block_row0 + wv * 32;

    __shared__ short lds_b[2][4096];   // [buf][ hi: 0..2047 | lo: 2048..4095 ]
    __shared__ int sidx[128];
    __shared__ unsigned char sflg[128];
    __shared__ float red[4];

    // ---- stage tile 0 (issued first so it overlaps A-conversion) ----
    {
        const short* gh = w_hi + wv * 512 + lane * 8;
        const short* gl = w_lo + wv * 512 + lane * 8;
        gload_lds16(gh, &lds_b[0][wv * 512]);
        gload_lds16(gl, &lds_b[0][2048 + wv * 512]);
    }

    // ---- A operand: 2 rowtiles x 2 k-chunks; A[m][k=q*8+j] ----
    float xa[2][2][8];
#pragma unroll
    for (int rt = 0; rt < 2; ++rt) {
        const float* xr = x + (size_t)(wave_row0 + rt * 16 + m) * DIM + q * 8;
        *(float4*)&xa[rt][0][0] = *(const float4*)(xr);
        *(float4*)&xa[rt][0][4] = *(const float4*)(xr + 4);
        *(float4*)&xa[rt][1][0] = *(const float4*)(xr + 32);
        *(float4*)&xa[rt][1][4] = *(const float4*)(xr + 36);
    }
    bf16x8 ah[2][2], al[2][2];
#pragma unroll
    for (int rt = 0; rt < 2; ++rt)
#pragma unroll
        for (int c = 0; c < 2; ++c)
#pragma unroll
            for (int j = 0; j < 8; ++j) {
                float f = xa[rt][c][j];
                short h = f2bf(f);
                ah[rt][c][j] = h;
                al[rt][c][j] = f2bf(f - bf2f(h));
            }

    float best[2][4], sec[2][4];
    int bidx[2][4];
#pragma unroll
    for (int rt = 0; rt < 2; ++rt)
#pragma unroll
        for (int r = 0; r < 4; ++r) {
            best[rt][r] = 3.4e38f;
            sec[rt][r] = 3.4e38f;
            bidx[rt][r] = 0;
        }

    float e2a = e2[m], e2b = e2[16 + m];   // tile 0's e2 (per-lane m)
    __syncthreads();                        // stage(0) visible to all waves

    for (int t = 0; t < KCODES / 32; ++t) {
        const int cur = t & 1;
        // stage tile t+1 into the other buffer (uniform branch on last iter)
        if (t < KCODES / 32 - 1) {
            const short* gh = w_hi + (size_t)(t + 1) * 2048 + wv * 512 + lane * 8;
            const short* gl = w_lo + (size_t)(t + 1) * 2048 + wv * 512 + lane * 8;
            gload_lds16(gh, &lds_b[cur ^ 1][wv * 512]);
            gload_lds16(gl, &lds_b[cur ^ 1][2048 + wv * 512]);
        }
        // prefetch next tile's e2 (wrap on last iter; value unused then)
        const int tn = (t + 1) & (KCODES / 32 - 1);
        float e2an = e2[tn * 32 + m];
        float e2bn = e2[tn * 32 + 16 + m];

        // B-frags from LDS: linear, conflict-free b128 (lane i -> byte 16*i)
        bf16x8 bh[2][2], bl[2][2];
#pragma unroll
        for (int ct = 0; ct < 2; ++ct)
#pragma unroll
            for (int kc = 0; kc < 2; ++kc) {
                int off = (ct * 2 + kc) * 512 + lane * 8;
                bh[ct][kc] = *(const bf16x8*)&lds_b[cur][off];
                bl[ct][kc] = *(const bf16x8*)&lds_b[cur][2048 + off];
            }

#pragma unroll
        for (int rt = 0; rt < 2; ++rt)
#pragma unroll
            for (int ct = 0; ct < 2; ++ct) {   // ct ascending: idx ascending
                float ei = ct ? e2b : e2a;
                f32x4 a = {ei, ei, ei, ei};
                a = __builtin_amdgcn_mfma_f32_16x16x32_bf16(al[rt][0], bh[ct][0], a, 0, 0, 0);
                a = __builtin_amdgcn_mfma_f32_16x16x32_bf16(ah[rt][0], bl[ct][0], a, 0, 0, 0);
                a = __builtin_amdgcn_mfma_f32_16x16x32_bf16(ah[rt][0], bh[ct][0], a, 0, 0, 0);
                a = __builtin_amdgcn_mfma_f32_16x16x32_bf16(al[rt][1], bh[ct][1], a, 0, 0, 0);
                a = __builtin_amdgcn_mfma_f32_16x16x32_bf16(ah[rt][1], bl[ct][1], a, 0, 0, 0);
                a = __builtin_amdgcn_mfma_f32_16x16x32_bf16(ah[rt][1], bh[ct][1], a, 0, 0, 0);
                int id = t * 32 + ct * 16 + m;
#pragma unroll
                for (int r = 0; r < 4; ++r) {
                    float g = a[r];
                    bool c = g < best[rt][r];
                    sec[rt][r] = fminf(sec[rt][r], fmaxf(g, best[rt][r]));
                    if (c) { best[rt][r] = g; bidx[rt][r] = id; }
                }
            }

        __syncthreads();   // drains stage(t+1) vmcnt + everyone's ds_reads
        e2a = e2an;
        e2b = e2bn;
    }

    // cross-lane reduce over the 16 m-lanes; tie -> lower idx (numpy rule)
#pragma unroll
    for (int off = 1; off < 16; off <<= 1)
#pragma unroll
        for (int rt = 0; rt < 2; ++rt)
#pragma unroll
            for (int r = 0; r < 4; ++r) {
                float ob = __shfl_xor(best[rt][r], off, 64);
                int oi = __shfl_xor(bidx[rt][r], off, 64);
                float os = __shfl_xor(sec[rt][r], off, 64);
                float mx = fmaxf(best[rt][r], ob);
                sec[rt][r] = fminf(fminf(sec[rt][r], os), mx);
                bool take = (ob < best[rt][r]) ||
                            (ob == best[rt][r] && oi < bidx[rt][r]);
                if (take) { best[rt][r] = ob; bidx[rt][r] = oi; }
            }

    if (m == 0) {
#pragma unroll
        for (int rt = 0; rt < 2; ++rt)
#pragma unroll
            for (int r = 0; r < 4; ++r) {
                int lr = wv * 32 + rt * 16 + q * 4 + r;
                sidx[lr] = bidx[rt][r];
                bool fl = (sec[rt][r] - best[rt][r]) < MARGIN;
                sflg[lr] = fl ? 1 : 0;
                if (fl) {
                    unsigned p = atomicAdd(flag_cnt, 1u);
                    flag_list[p] = (unsigned)(block_row0 + lr);
                }
            }
    }
    __syncthreads();

    // ---- output pass: 2 x 64 rows, 4 threads/row ----
    float lsum = 0.f;
    const int rl = tid >> 2, part = tid & 3;
#pragma unroll
    for (int p = 0; p < 2; ++p) {
        int lr = p * 64 + rl;
        int grow = block_row0 + lr;
        if (!sflg[lr]) {
            int bi = sidx[lr];
            const float* xs = x + (size_t)grow * DIM + part * 16;
            const float* ws = w + (size_t)bi * DIM + part * 16;
            float* os = out_q + (size_t)grow * DIM + part * 16;
#pragma unroll
            for (int i = 0; i < 4; ++i) {
                float4 xv = *(const float4*)(xs + 4 * i);
                float4 wv4 = *(const float4*)(ws + 4 * i);
                float d0 = wv4.x - xv.x, d1 = wv4.y - xv.y;
                float d2 = wv4.z - xv.z, d3 = wv4.w - xv.w;
                lsum = fmaf(d0, d0, lsum);
                lsum = fmaf(d1, d1, lsum);
                lsum = fmaf(d2, d2, lsum);
                lsum = fmaf(d3, d3, lsum);
                float4 o = {xv.x + d0, xv.y + d1, xv.z + d2, xv.w + d3};
                *(float4*)(os + 4 * i) = o;
            }
            if (part == 0) out_idx[grow] = (float)bi;
        }
    }

    for (int off = 32; off > 0; off >>= 1) lsum += __shfl_down(lsum, off, 64);
    if ((tid & 63) == 0) red[tid >> 6] = lsum;
    __syncthreads();
    if (tid == 0) {
        float s = (red[0] + red[1]) + (red[2] + red[3]);
        atomicAdd(out_loss, s * LOSS_SCALE);
    }
}

// Exact re-scan of flagged rows (bit-exact numerics). b128 LDS reads; the fmaf
// chain stays in ascending-d order -> bit-identical dots.
#define CH 16
__global__ __launch_bounds__(256) void vq_cleanup(
        const float* __restrict__ x, const float* __restrict__ w,
        const float* __restrict__ e2,
        const unsigned* __restrict__ flag_cnt,
        const unsigned* __restrict__ flag_list,
        float* __restrict__ out_q, float* __restrict__ out_loss,
        float* __restrict__ out_idx) {
    __shared__ float xs[CH][68];
    __shared__ float wt[128][68];
    __shared__ float sx2[CH];
    const int tid = threadIdx.x;
    const int rowsub = tid >> 4;    // 0..15
    const int kslot = tid & 15;
    const unsigned cnt = *flag_cnt;

    for (unsigned base = blockIdx.x * CH; base < cnt; base += gridDim.x * CH) {
        const int nrows = (int)min((unsigned)CH, cnt - base);
        __syncthreads();
        {
            int rr = tid >> 4, sg = tid & 15;
            if (rr < nrows) {
                unsigned grow = flag_list[base + rr];
                *(float4*)&xs[rr][sg * 4] =
                    *(const float4*)(x + (size_t)grow * DIM + sg * 4);
            }
        }
        __syncthreads();
        if (tid < nrows) {
            float s = 0.f;
#pragma unroll
            for (int d = 0; d < DIM; ++d) s = fmaf(xs[tid][d], xs[tid][d], s);
            sx2[tid] = s;
        }

        unsigned long long kmin = ~0ULL;
        for (int tile = 0; tile < KCODES / 128; ++tile) {
            __syncthreads();
#pragma unroll
            for (int i = 0; i < 8; ++i) {
                int f = tid + i * 256;
                int code = f >> 4, sg = f & 15;
                *(float4*)&wt[code][sg * 4] =
                    *(const float4*)(w + (size_t)(tile * 128 + code) * DIM + sg * 4);
            }
            __syncthreads();
            if (rowsub < nrows) {
#pragma unroll
                for (int j = 0; j < 8; ++j) {
                    int cl = j * 16 + kslot;
                    int code = tile * 128 + cl;
                    float dot = 0.f;
#pragma unroll
                    for (int d4 = 0; d4 < 16; ++d4) {
                        float4 wv4 = *(const float4*)&wt[cl][d4 * 4];
                        float4 xv4 = *(const float4*)&xs[rowsub][d4 * 4];
                        dot = fmaf(wv4.x, xv4.x, dot);
                        dot = fmaf(wv4.y, xv4.y, dot);
                        dot = fmaf(wv4.z, xv4.z, dot);
                        dot = fmaf(wv4.w, xv4.w, dot);
                    }
                    float dist = (sx2[rowsub] + e2[code]) - 2.0f * dot;
                    unsigned long long key =
                        ((unsigned long long)__float_as_uint(dist) << 32) |
                        (unsigned)code;
                    kmin = kmin < key ? kmin : key;
                }
            }
        }
#pragma unroll
        for (int off = 1; off < 16; off <<= 1) {
            unsigned long long o = __shfl_xor(kmin, off, 64);
            kmin = kmin < o ? kmin : o;
        }
        if (rowsub < nrows) {
            int bi = (int)(unsigned)(kmin & 0xFFFFFFFFu);
            unsigned grow = flag_list[base + rowsub];
            float4 x4 = *(float4*)&xs[rowsub][kslot * 4];
            float4 w4 = *(const float4*)(w + (size_t)bi * DIM + kslot * 4);
            float d0 = w4.x - x4.x, d1 = w4.y - x4.y;
            float d2 = w4.z - x4.z, d3 = w4.w - x4.w;
            float ls = 0.f;
            ls = fmaf(d0, d0, ls);
            ls = fmaf(d1, d1, ls);
            ls = fmaf(d2, d2, ls);
            ls = fmaf(d3, d3, ls);
            float4 o = {x4.x + d0, x4.y + d1, x4.z + d2, x4.w + d3};
            *(float4*)(out_q + (size_t)grow * DIM + kslot * 4) = o;
            if (kslot == 0) out_idx[grow] = (float)bi;
#pragma unroll
            for (int off = 1; off < 16; off <<= 1)
                ls += __shfl_xor(ls, off, 64);
            if (kslot == 0) atomicAdd(out_loss, ls * LOSS_SCALE);
        }
    }
}

extern "C" void kernel_launch(void* const* d_in, const int* in_sizes, int n_in,
                              void* d_out, int out_size, void* d_ws, size_t ws_size,
                              hipStream_t stream) {
    const float* x = (const float*)d_in[0];   // [N, D]
    const float* w = (const float*)d_in[1];   // [K, D]

    float* out_q    = (float*)d_out;
    float* out_loss = (float*)d_out + (size_t)NROWS * DIM;
    float* out_idx  = out_loss + 1;

    // ws: e2 (4KB) | w_hi frag-order (128KB) | w_lo (128KB) | cnt | list (512KB)
    float* e2 = (float*)d_ws;
    short* w_hi = (short*)(e2 + KCODES);
    short* w_lo = w_hi + (size_t)KCODES * DIM;
    unsigned* cnt = (unsigned*)(w_lo + (size_t)KCODES * DIM);
    unsigned* list = cnt + 1;

    prep_w<<<(KCODES + 255) / 256, 256, 0, stream>>>(w, e2, w_hi, w_lo,
                                                     out_loss, cnt);
    vq_main<<<NROWS / 128, 256, 0, stream>>>(x, w, e2, w_hi, w_lo,
                                             out_q, out_loss, out_idx, cnt, list);
    vq_cleanup<<<256, 256, 0, stream>>>(x, w, e2, cnt, list,
                                        out_q, out_loss, out_idx);
}